// Round 1
// baseline (41.363 us; speedup 1.0000x reference)
//
#include <hip/hip_runtime.h>
#include <hip/hip_bf16.h>

#define SLEN 4096
#define NH 16
#define PDIM 64
#define NDIM 128
#define NBH 32  // b*h

typedef __attribute__((ext_vector_type(8))) short short8;
typedef __attribute__((ext_vector_type(4))) float f32x4;

// ---------------- Kernel 1: suffix-sum weights w[t] = exp(sum_{t'>t} A[t']) ----
__global__ void suffix_weights_kernel(const float* __restrict__ A, float* __restrict__ w) {
    int bh = blockIdx.x;
    int b = bh >> 4, h = bh & 15;
    int tid = threadIdx.x;
    const float* Ab = A + ((size_t)b * SLEN * NH) + h;  // A[b][t][h], stride NH
    float loc[16];
    float s = 0.f;
    int t0 = tid * 16;
#pragma unroll
    for (int i = 0; i < 16; ++i) { s += Ab[(size_t)(t0 + i) * NH]; loc[i] = s; }
    __shared__ float sums[256];
    sums[tid] = s;
    __syncthreads();
    for (int off = 1; off < 256; off <<= 1) {
        float v = (tid >= off) ? sums[tid - off] : 0.f;
        __syncthreads();
        sums[tid] += v;
        __syncthreads();
    }
    float total = sums[255];
    float excl = sums[tid] - s;  // exclusive prefix of this thread's chunk
    float* wr = w + (size_t)bh * SLEN;
#pragma unroll
    for (int i = 0; i < 16; ++i) wr[t0 + i] = expf(total - (excl + loc[i]));
}

__device__ __forceinline__ short f2bf(float x) {
    __hip_bfloat16 h = __float2bfloat16(x);
    return *reinterpret_cast<short*>(&h);
}

// ---------------- Kernel 2: K-split weighted outer-product GEMM ----------------
// out[p,n] += sum_t w[t]*X[t,p]*B[t,n] over this block's K-slice.
// Block: 256 threads = 4 waves in 2x2 grid; wave owns 32p x 64n quadrant
// (2x4 tiles of 16x16, mfma_f32_16x16x32_bf16).
__global__ __launch_bounds__(256) void state_gemm_kernel(
    const float* __restrict__ X, const float* __restrict__ Bm,
    const float* __restrict__ w, float* __restrict__ partial, int kb) {
    int ks = blockIdx.x;
    int bh = blockIdx.y;
    int b = bh >> 4, h = bh & 15;
    int tid = threadIdx.x;
    int lane = tid & 63, wid = tid >> 6;
    int wp = wid & 1, wn = wid >> 1;
    int p0 = wp * 32, n0 = wn * 64;
    int m = lane & 15;   // row/col within 16x16 frag
    int kg = lane >> 4;  // k-group: k = kg*8 + j

    size_t baseX = (size_t)b * SLEN * NH * PDIM + (size_t)h * PDIM;
    size_t baseB = (size_t)b * SLEN * NH * NDIM + (size_t)h * NDIM;
    const float* wr = w + (size_t)bh * SLEN;

    f32x4 acc[2][4];
#pragma unroll
    for (int i = 0; i < 2; ++i)
#pragma unroll
        for (int j = 0; j < 4; ++j) acc[i][j] = (f32x4){0.f, 0.f, 0.f, 0.f};

    int tstart = ks * kb;
    for (int kt = 0; kt < kb; kt += 32) {
        int tb = tstart + kt + kg * 8;
        short8 afr[2];
        short8 bfr[4];
#pragma unroll
        for (int j = 0; j < 8; ++j) {
            int t = tb + j;
            float wv = wr[t];
            const float* xp = X + baseX + (size_t)t * (NH * PDIM);
            const float* bp = Bm + baseB + (size_t)t * (NH * NDIM);
#pragma unroll
            for (int pi = 0; pi < 2; ++pi)
                afr[pi][j] = f2bf(xp[p0 + pi * 16 + m] * wv);
#pragma unroll
            for (int ni = 0; ni < 4; ++ni)
                bfr[ni][j] = f2bf(bp[n0 + ni * 16 + m]);
        }
#pragma unroll
        for (int pi = 0; pi < 2; ++pi)
#pragma unroll
            for (int ni = 0; ni < 4; ++ni)
                acc[pi][ni] = __builtin_amdgcn_mfma_f32_16x16x32_bf16(
                    afr[pi], bfr[ni], acc[pi][ni], 0, 0, 0);
    }

    float* outp = partial + (size_t)ks * (NBH * PDIM * NDIM) + (size_t)bh * (PDIM * NDIM);
#pragma unroll
    for (int pi = 0; pi < 2; ++pi)
#pragma unroll
        for (int ni = 0; ni < 4; ++ni)
#pragma unroll
            for (int r = 0; r < 4; ++r) {
                int p = p0 + pi * 16 + kg * 4 + r;  // C/D: row=(lane>>4)*4+reg
                int n = n0 + ni * 16 + m;           // C/D: col=lane&15
                outp[p * NDIM + n] = acc[pi][ni][r];
            }
}

// ---------------- Kernel 3: reduce K-split partials -----------------------------
__global__ void reduce_kernel(const float* __restrict__ partial, float* __restrict__ out,
                              int ksplit) {
    int i = blockIdx.x * 256 + threadIdx.x;
    float s = 0.f;
    for (int ks = 0; ks < ksplit; ++ks) s += partial[(size_t)ks * (NBH * PDIM * NDIM) + i];
    out[i] = s;
}

extern "C" void kernel_launch(void* const* d_in, const int* in_sizes, int n_in,
                              void* d_out, int out_size, void* d_ws, size_t ws_size,
                              hipStream_t stream) {
    const float* X = (const float*)d_in[0];
    const float* A = (const float*)d_in[1];
    const float* Bm = (const float*)d_in[2];
    // d_in[3] (C) is unused by the reference.
    float* out = (float*)d_out;

    float* w = (float*)d_ws;
    size_t wbytes = (size_t)NBH * SLEN * sizeof(float);
    float* partial = (float*)((char*)d_ws + wbytes);
    size_t slice_bytes = (size_t)NBH * PDIM * NDIM * sizeof(float);

    int ksplit = 1;
    const int cand[4] = {16, 8, 4, 2};
    for (int i = 0; i < 4; ++i) {
        if (ws_size >= wbytes + (size_t)cand[i] * slice_bytes) { ksplit = cand[i]; break; }
    }

    suffix_weights_kernel<<<NBH, 256, 0, stream>>>(A, w);

    if (ksplit == 1) {
        // degenerate fallback: single K-slice straight into out
        state_gemm_kernel<<<dim3(1, NBH), 256, 0, stream>>>(X, Bm, w, out, SLEN);
        return;
    }
    state_gemm_kernel<<<dim3(ksplit, NBH), 256, 0, stream>>>(X, Bm, w, partial, SLEN / ksplit);
    int nout = NBH * PDIM * NDIM;
    reduce_kernel<<<nout / 256, 256, 0, stream>>>(partial, out, ksplit);
}

// Round 2
// 36.816 us; speedup vs baseline: 1.1235x; 1.1235x over previous
//
#include <hip/hip_runtime.h>
#include <hip/hip_bf16.h>

#define SLEN 4096
#define NH 16
#define PDIM 64
#define NDIM 128
#define NBH 32  // b*h

typedef __attribute__((ext_vector_type(8))) short short8;
typedef __attribute__((ext_vector_type(4))) float f32x4;

// ---------------- Kernel 1: suffix-sum weights w[t] = exp(sum_{t'>t} A[t']) ----
__global__ void suffix_weights_kernel(const float* __restrict__ A, float* __restrict__ w) {
    int bh = blockIdx.x;
    int b = bh >> 4, h = bh & 15;
    int tid = threadIdx.x;
    const float* Ab = A + ((size_t)b * SLEN * NH) + h;  // A[b][t][h], stride NH
    float loc[16];
    float s = 0.f;
    int t0 = tid * 16;
#pragma unroll
    for (int i = 0; i < 16; ++i) { s += Ab[(size_t)(t0 + i) * NH]; loc[i] = s; }
    __shared__ float sums[256];
    sums[tid] = s;
    __syncthreads();
    for (int off = 1; off < 256; off <<= 1) {
        float v = (tid >= off) ? sums[tid - off] : 0.f;
        __syncthreads();
        sums[tid] += v;
        __syncthreads();
    }
    float total = sums[255];
    float excl = sums[tid] - s;  // exclusive prefix of this thread's chunk
    float* wr = w + (size_t)bh * SLEN;
#pragma unroll
    for (int i = 0; i < 16; ++i) wr[t0 + i] = expf(total - (excl + loc[i]));
}

__device__ __forceinline__ short f2bf(float x) {
    __hip_bfloat16 h = __float2bfloat16(x);
    return *reinterpret_cast<short*>(&h);
}

// ---------------- Kernel 2: K-split weighted outer-product GEMM ----------------
// out[p,n] += sum_t w[t]*X[t,p]*B[t,n] over this block's K-slice.
// Grid: (ksplit, nsplit=2, NBH). Block: 256 thr = 4 waves (2p x 2n),
// wave owns 32p x 32n quadrant = 2x2 frags of mfma_f32_16x16x32_bf16.
// Register-double-buffered K loop (32-t tiles, ping-pong).
__global__ __launch_bounds__(256) void state_gemm_kernel(
    const float* __restrict__ X, const float* __restrict__ Bm,
    const float* __restrict__ w, float* __restrict__ partial, int kb) {
    int ks = blockIdx.x;
    int ns = blockIdx.y;
    int bh = blockIdx.z;
    int b = bh >> 4, h = bh & 15;
    int tid = threadIdx.x;
    int lane = tid & 63, wid = tid >> 6;
    int wp = wid & 1, wn = wid >> 1;
    int p0 = wp * 32;
    int n0 = ns * 64 + wn * 32;
    int m = lane & 15;   // M/N index within 16x16 frag
    int kg = lane >> 4;  // k-group: k = kg*8 + j

    // per-lane hoisted base pointers (64-bit math once)
    const float* xp0 = X + (size_t)b * SLEN * NH * PDIM + (size_t)h * PDIM + p0 + m;
    const float* bp0 = Bm + (size_t)b * SLEN * NH * NDIM + (size_t)h * NDIM + n0 + m;
    const float* wr = w + (size_t)bh * SLEN;

    f32x4 acc[2][2];
#pragma unroll
    for (int i = 0; i < 2; ++i)
#pragma unroll
        for (int j = 0; j < 2; ++j) acc[i][j] = (f32x4){0.f, 0.f, 0.f, 0.f};

    int tstart = ks * kb;
    // lane's first t within a tile starting at `tt`: tt + kg*8
#define LOADM(tt, AF, BF)                                                      \
    {                                                                          \
        int tb = (tt) + kg * 8;                                                \
        const float* xp = xp0 + (size_t)tb * (NH * PDIM);                      \
        const float* bp = bp0 + (size_t)tb * (NH * NDIM);                      \
        const float* wp_ = wr + tb;                                            \
        _Pragma("unroll") for (int j = 0; j < 8; ++j) {                        \
            float wv = wp_[j];                                                 \
            AF[0][j] = f2bf(xp[(size_t)j * (NH * PDIM)] * wv);                 \
            AF[1][j] = f2bf(xp[(size_t)j * (NH * PDIM) + 16] * wv);            \
            BF[0][j] = f2bf(bp[(size_t)j * (NH * NDIM)]);                      \
            BF[1][j] = f2bf(bp[(size_t)j * (NH * NDIM) + 16]);                 \
        }                                                                      \
    }

#define MFMAM(AF, BF)                                                          \
    {                                                                          \
        _Pragma("unroll") for (int pi = 0; pi < 2; ++pi)                       \
            _Pragma("unroll") for (int ni = 0; ni < 2; ++ni)                   \
                acc[pi][ni] = __builtin_amdgcn_mfma_f32_16x16x32_bf16(         \
                    AF[pi], BF[ni], acc[pi][ni], 0, 0, 0);                     \
    }

    short8 a0[2], b0[2], a1[2], b1[2];
    LOADM(tstart, a0, b0);
    for (int kt = 0; kt < kb - 64; kt += 64) {
        LOADM(tstart + kt + 32, a1, b1);
        MFMAM(a0, b0);
        LOADM(tstart + kt + 64, a0, b0);
        MFMAM(a1, b1);
    }
    LOADM(tstart + kb - 32, a1, b1);
    MFMAM(a0, b0);
    MFMAM(a1, b1);
#undef LOADM
#undef MFMAM

    float* outp = partial + ((size_t)ks * NBH + bh) * (PDIM * NDIM);
#pragma unroll
    for (int pi = 0; pi < 2; ++pi)
#pragma unroll
        for (int ni = 0; ni < 2; ++ni)
#pragma unroll
            for (int r = 0; r < 4; ++r) {
                int p = p0 + pi * 16 + kg * 4 + r;  // C/D: row=(lane>>4)*4+reg
                int n = n0 + ni * 16 + m;           // C/D: col=lane&15
                outp[p * NDIM + n] = acc[pi][ni][r];
            }
}

// ---------------- Kernel 3: reduce K-split partials (float4) --------------------
__global__ void reduce_kernel(const float* __restrict__ partial, float* __restrict__ out,
                              int ksplit) {
    int i = blockIdx.x * 256 + threadIdx.x;  // float4 index
    const f32x4* pp = (const f32x4*)partial;
    f32x4 s = (f32x4){0.f, 0.f, 0.f, 0.f};
    for (int ks = 0; ks < ksplit; ++ks) {
        f32x4 v = pp[(size_t)ks * (NBH * PDIM * NDIM / 4) + i];
        s.x += v.x; s.y += v.y; s.z += v.z; s.w += v.w;
    }
    ((f32x4*)out)[i] = s;
}

extern "C" void kernel_launch(void* const* d_in, const int* in_sizes, int n_in,
                              void* d_out, int out_size, void* d_ws, size_t ws_size,
                              hipStream_t stream) {
    const float* X = (const float*)d_in[0];
    const float* A = (const float*)d_in[1];
    const float* Bm = (const float*)d_in[2];
    // d_in[3] (C) is unused by the reference.
    float* out = (float*)d_out;

    float* w = (float*)d_ws;
    size_t wbytes = (size_t)NBH * SLEN * sizeof(float);
    float* partial = (float*)((char*)d_ws + wbytes);
    size_t slice_bytes = (size_t)NBH * PDIM * NDIM * sizeof(float);

    int ksplit = 1;
    const int cand[4] = {16, 8, 4, 2};
    for (int i = 0; i < 4; ++i) {
        if (ws_size >= wbytes + (size_t)cand[i] * slice_bytes) { ksplit = cand[i]; break; }
    }

    suffix_weights_kernel<<<NBH, 256, 0, stream>>>(A, w);

    if (ksplit == 1) {
        // degenerate fallback: single K-slice straight into out (n-split blocks disjoint)
        state_gemm_kernel<<<dim3(1, 2, NBH), 256, 0, stream>>>(X, Bm, w, out, SLEN);
        return;
    }
    state_gemm_kernel<<<dim3(ksplit, 2, NBH), 256, 0, stream>>>(X, Bm, w, partial, SLEN / ksplit);
    int nout4 = NBH * PDIM * NDIM / 4;
    reduce_kernel<<<nout4 / 256, 256, 0, stream>>>(partial, out, ksplit);
}

// Round 3
// 35.007 us; speedup vs baseline: 1.1816x; 1.0517x over previous
//
#include <hip/hip_runtime.h>
#include <hip/hip_bf16.h>

#define SLEN 4096
#define NH 16
#define PDIM 64
#define NDIM 128
#define NBH 32   // b*h
#define KSPLIT 16
#define TT 64    // t per LDS tile

typedef __attribute__((ext_vector_type(8))) short short8;
typedef __attribute__((ext_vector_type(4))) float f32x4;

// swizzle: spreads both ds_read_b128 (rows consecutive) and transpose
// ds_write_b32 (rows stride-4) across all 8 16B slots of a 128B row
__device__ __forceinline__ int swz(int r) { return ((r & 7) ^ ((r >> 2) & 7)) << 4; }

__device__ __forceinline__ unsigned short f2bfu(float x) {
    __hip_bfloat16 h = __float2bfloat16(x);
    return *reinterpret_cast<unsigned short*>(&h);
}
__device__ __forceinline__ unsigned pack2(float lo, float hi) {
    return (unsigned)f2bfu(lo) | ((unsigned)f2bfu(hi) << 16);
}

// ---------------- Kernel 1: suffix weights w[t] = exp(sum_{t'>t} A[t']) -------
__global__ void suffix_weights_kernel(const float* __restrict__ A, float* __restrict__ w) {
    int bh = blockIdx.x;
    int b = bh >> 4, h = bh & 15;
    int tid = threadIdx.x;
    const float* Ab = A + ((size_t)b * SLEN * NH) + h;  // A[b][t][h], stride NH
    float loc[16];
    float s = 0.f;
    int t0 = tid * 16;
#pragma unroll
    for (int i = 0; i < 16; ++i) { s += Ab[(size_t)(t0 + i) * NH]; loc[i] = s; }
    __shared__ float sums[256];
    sums[tid] = s;
    __syncthreads();
    for (int off = 1; off < 256; off <<= 1) {
        float v = (tid >= off) ? sums[tid - off] : 0.f;
        __syncthreads();
        sums[tid] += v;
        __syncthreads();
    }
    float total = sums[255];
    float excl = sums[tid] - s;
    float* wr = w + (size_t)bh * SLEN;
#pragma unroll
    for (int i = 0; i < 16; ++i) wr[t0 + i] = expf(total - (excl + loc[i]));
}

// ---------------- Kernel 2: LDS-staged K-split weighted GEMM ------------------
// out[p,n] += sum_t (w[t]*X[t,p]) * B[t,n] over this block's K-slice.
// Block: 512 thr = 8 waves (2p x 4n); wave = 32p x 32n (2x2 frags 16x16x32).
// LDS per buffer: A=[64p][64t] bf16 (8KB) + B=[128n][64t] bf16 (16KB), dbuf.
__global__ __launch_bounds__(512) void state_gemm_kernel(
    const float* __restrict__ X, const float* __restrict__ Bm,
    const float* __restrict__ w, float* __restrict__ partial, int kb, int nt) {
    int ks = blockIdx.x;
    int bh = blockIdx.y;
    int b = bh >> 4, h = bh & 15;
    int tid = threadIdx.x;
    int lane = tid & 63, wid = tid >> 6;
    int wp = wid & 1, wn = wid >> 1;
    int p0 = wp * 32, n0 = wn * 32;
    int m = lane & 15, kg = lane >> 4;

    __shared__ __align__(16) char lds[2][24576];  // A at 0, B at 8192

    // staging maps (coalesced float4 rows from global)
    int cx = tid & 15, tpx = tid >> 4;  // X: p=4cx+i, t-pair tpx (0..31)
    int cb = tid & 31, tpb = tid >> 5;  // B: n=4cb+i, t-pair tpb (0..15) +16*ib

    const float* Xb = X + (size_t)b * SLEN * NH * PDIM + (size_t)h * PDIM;
    const float* Bb = Bm + (size_t)b * SLEN * NH * NDIM + (size_t)h * NDIM;
    const float* wr = w + (size_t)bh * SLEN;
    int t0 = ks * kb;

    const float* xsrc = Xb + (size_t)(t0 + 2 * tpx) * (NH * PDIM) + 4 * cx;
    const float* bsrc = Bb + (size_t)(t0 + 2 * tpb) * (NH * NDIM) + 4 * cb;
    const float* wsrc = wr + t0 + 2 * tpx;

    // write byte offsets (swizzled)
    int wX[4], wB0[4], wB1[4];
#pragma unroll
    for (int i = 0; i < 4; ++i) {
        int rx = 4 * cx + i;
        wX[i] = (rx * 128 + 4 * tpx) ^ swz(rx);
        int rb = 4 * cb + i;
        wB0[i] = 8192 + ((rb * 128 + 4 * tpb) ^ swz(rb));
        wB1[i] = 8192 + ((rb * 128 + 4 * (tpb + 16)) ^ swz(rb));
    }
    // read byte offsets (swizzled)
    int rA[2][2], rB[2][2];
#pragma unroll
    for (int pi = 0; pi < 2; ++pi)
#pragma unroll
        for (int kk = 0; kk < 2; ++kk) {
            int r = p0 + pi * 16 + m;
            rA[pi][kk] = (r * 128 + kk * 64 + kg * 16) ^ swz(r);
        }
#pragma unroll
    for (int ni = 0; ni < 2; ++ni)
#pragma unroll
        for (int kk = 0; kk < 2; ++kk) {
            int rn = n0 + ni * 16 + m;
            rB[ni][kk] = 8192 + ((rn * 128 + kk * 64 + kg * 16) ^ swz(rn));
        }

    f32x4 acc[2][2];
#pragma unroll
    for (int i = 0; i < 2; ++i)
#pragma unroll
        for (int j = 0; j < 2; ++j) acc[i][j] = (f32x4){0.f, 0.f, 0.f, 0.f};

    f32x4 xr0, xr1, br[2][2];
    float wv0, wv1;

#define LOADR(it)                                                              \
    {                                                                          \
        size_t ax = (size_t)(it) * (TT * NH * PDIM);                           \
        size_t ab = (size_t)(it) * (TT * NH * NDIM);                           \
        xr0 = *(const f32x4*)(xsrc + ax);                                      \
        xr1 = *(const f32x4*)(xsrc + ax + NH * PDIM);                          \
        wv0 = wsrc[(it) * TT];                                                 \
        wv1 = wsrc[(it) * TT + 1];                                             \
        br[0][0] = *(const f32x4*)(bsrc + ab);                                 \
        br[0][1] = *(const f32x4*)(bsrc + ab + NH * NDIM);                     \
        br[1][0] = *(const f32x4*)(bsrc + ab + 32 * NH * NDIM);                \
        br[1][1] = *(const f32x4*)(bsrc + ab + 33 * NH * NDIM);                \
    }

#define CVTW(buf)                                                              \
    {                                                                          \
        char* dst = lds[buf];                                                  \
        _Pragma("unroll") for (int i = 0; i < 4; ++i) {                        \
            *(unsigned*)(dst + wX[i]) = pack2(xr0[i] * wv0, xr1[i] * wv1);     \
            *(unsigned*)(dst + wB0[i]) = pack2(br[0][0][i], br[0][1][i]);      \
            *(unsigned*)(dst + wB1[i]) = pack2(br[1][0][i], br[1][1][i]);      \
        }                                                                      \
    }

#define COMPUTE(buf)                                                           \
    {                                                                          \
        const char* src = lds[buf];                                            \
        short8 af[2][2], bf[2][2];                                             \
        _Pragma("unroll") for (int pi = 0; pi < 2; ++pi)                       \
            _Pragma("unroll") for (int kk = 0; kk < 2; ++kk)                   \
                af[pi][kk] = *(const short8*)(src + rA[pi][kk]);               \
        _Pragma("unroll") for (int ni = 0; ni < 2; ++ni)                       \
            _Pragma("unroll") for (int kk = 0; kk < 2; ++kk)                   \
                bf[ni][kk] = *(const short8*)(src + rB[ni][kk]);               \
        _Pragma("unroll") for (int kk = 0; kk < 2; ++kk)                       \
            _Pragma("unroll") for (int pi = 0; pi < 2; ++pi)                   \
                _Pragma("unroll") for (int ni = 0; ni < 2; ++ni)               \
                    acc[pi][ni] = __builtin_amdgcn_mfma_f32_16x16x32_bf16(     \
                        af[pi][kk], bf[ni][kk], acc[pi][ni], 0, 0, 0);         \
    }

    LOADR(0);
    CVTW(0);
    __syncthreads();
    int cur = 0;
    for (int it = 0; it < nt; ++it) {
        if (it + 1 < nt) LOADR(it + 1);
        COMPUTE(cur);
        __syncthreads();
        if (it + 1 < nt) CVTW(cur ^ 1);
        __syncthreads();
        cur ^= 1;
    }
#undef LOADR
#undef CVTW
#undef COMPUTE

    float* outp = partial + ((size_t)ks * NBH + bh) * (PDIM * NDIM);
#pragma unroll
    for (int pi = 0; pi < 2; ++pi)
#pragma unroll
        for (int ni = 0; ni < 2; ++ni)
#pragma unroll
            for (int r = 0; r < 4; ++r) {
                int p = p0 + pi * 16 + kg * 4 + r;  // C/D: row=(lane>>4)*4+reg
                int n = n0 + ni * 16 + m;           // C/D: col=lane&15
                outp[p * NDIM + n] = acc[pi][ni][r];
            }
}

// ---------------- Kernel 3: reduce K-split partials (float4) -------------------
__global__ void reduce_kernel(const float* __restrict__ partial, float* __restrict__ out,
                              int ksplit) {
    int i = blockIdx.x * 256 + threadIdx.x;  // float4 index
    const f32x4* pp = (const f32x4*)partial;
    f32x4 s = (f32x4){0.f, 0.f, 0.f, 0.f};
    for (int ks = 0; ks < ksplit; ++ks) {
        f32x4 v = pp[(size_t)ks * (NBH * PDIM * NDIM / 4) + i];
        s.x += v.x; s.y += v.y; s.z += v.z; s.w += v.w;
    }
    ((f32x4*)out)[i] = s;
}

extern "C" void kernel_launch(void* const* d_in, const int* in_sizes, int n_in,
                              void* d_out, int out_size, void* d_ws, size_t ws_size,
                              hipStream_t stream) {
    const float* X = (const float*)d_in[0];
    const float* A = (const float*)d_in[1];
    const float* Bm = (const float*)d_in[2];
    // d_in[3] (C) is unused by the reference.
    float* out = (float*)d_out;

    float* w = (float*)d_ws;
    size_t wbytes = (size_t)NBH * SLEN * sizeof(float);
    float* partial = (float*)((char*)d_ws + wbytes);
    size_t slice_bytes = (size_t)NBH * PDIM * NDIM * sizeof(float);

    suffix_weights_kernel<<<NBH, 256, 0, stream>>>(A, w);

    if (ws_size < wbytes + (size_t)KSPLIT * slice_bytes) {
        // degenerate fallback: single K-slice straight into out
        state_gemm_kernel<<<dim3(1, NBH), 512, 0, stream>>>(X, Bm, w, out, SLEN, SLEN / TT);
        return;
    }
    state_gemm_kernel<<<dim3(KSPLIT, NBH), 512, 0, stream>>>(X, Bm, w, partial,
                                                             SLEN / KSPLIT, SLEN / KSPLIT / TT);
    int nout4 = NBH * PDIM * NDIM / 4;
    reduce_kernel<<<nout4 / 256, 256, 0, stream>>>(partial, out, KSPLIT);
}

// Round 4
// 32.022 us; speedup vs baseline: 1.2917x; 1.0932x over previous
//
#include <hip/hip_runtime.h>
#include <hip/hip_bf16.h>

#define SLEN 4096
#define NH 16
#define PDIM 64
#define NDIM 128
#define NBH 32   // b*h
#define KSPLIT 16
#define TT 64    // t per LDS tile

typedef __attribute__((ext_vector_type(8))) short short8;
typedef __attribute__((ext_vector_type(4))) float f32x4;

// swizzle: spreads both ds_read_b128 (rows consecutive) and transpose
// ds_write_b32 (rows stride-4) across all 8 16B slots of a 128B row
__device__ __forceinline__ int swz(int r) { return ((r & 7) ^ ((r >> 2) & 7)) << 4; }

__device__ __forceinline__ unsigned short f2bfu(float x) {
    __hip_bfloat16 h = __float2bfloat16(x);
    return *reinterpret_cast<unsigned short*>(&h);
}
__device__ __forceinline__ unsigned pack2(float lo, float hi) {
    return (unsigned)f2bfu(lo) | ((unsigned)f2bfu(hi) << 16);
}

// ---------------- Fused kernel: in-block suffix weights + LDS-staged GEMM -----
// out[p,n] += sum_t (w[t]*X[t,p]) * B[t,n] over this block's K-slice, where
// w[t] = exp(sum_{t'>t} A[t']) computed in-block (tail sum + LDS scan).
// Block: 512 thr = 8 waves (2p x 4n); wave = 32p x 32n (2x2 frags 16x16x32).
// LDS per buffer: A=[64p][64t] bf16 (8KB) + B=[128n][64t] bf16 (16KB), dbuf.
template <int KB, int NT>
__global__ __launch_bounds__(512) void state_gemm_kernel(
    const float* __restrict__ X, const float* __restrict__ Bm,
    const float* __restrict__ A, float* __restrict__ partial) {
    int ks = blockIdx.x;
    int bh = blockIdx.y;
    int b = bh >> 4, h = bh & 15;
    int tid = threadIdx.x;
    int lane = tid & 63, wid = tid >> 6;
    int wp = wid & 1, wn = wid >> 1;
    int p0 = wp * 32, n0 = wn * 32;
    int m = lane & 15, kg = lane >> 4;

    __shared__ __align__(16) char lds[2][24576];  // A at 0, B at 8192
    __shared__ float scratch[512];
    __shared__ float wlds[KB];

    // staging maps (coalesced float4 rows from global)
    int cx = tid & 15, tpx = tid >> 4;  // X: p=4cx+i, t-pair tpx (0..31)
    int cb = tid & 31, tpb = tid >> 5;  // B: n=4cb+i, t-pair tpb (0..15) +16*ib

    const float* Xb = X + (size_t)b * SLEN * NH * PDIM + (size_t)h * PDIM;
    const float* Bb = Bm + (size_t)b * SLEN * NH * NDIM + (size_t)h * NDIM;
    const float* Ab = A + (size_t)b * SLEN * NH + h;  // stride NH
    int t0 = ks * KB;

    const float* xsrc = Xb + (size_t)(t0 + 2 * tpx) * (NH * PDIM) + 4 * cx;
    const float* bsrc = Bb + (size_t)(t0 + 2 * tpb) * (NH * NDIM) + 4 * cb;

    // write byte offsets (swizzled)
    int wX[4], wB0[4], wB1[4];
#pragma unroll
    for (int i = 0; i < 4; ++i) {
        int rx = 4 * cx + i;
        wX[i] = (rx * 128 + 4 * tpx) ^ swz(rx);
        int rb = 4 * cb + i;
        wB0[i] = 8192 + ((rb * 128 + 4 * tpb) ^ swz(rb));
        wB1[i] = 8192 + ((rb * 128 + 4 * (tpb + 16)) ^ swz(rb));
    }
    // read byte offsets (swizzled)
    int rA[2][2], rB[2][2];
#pragma unroll
    for (int pi = 0; pi < 2; ++pi)
#pragma unroll
        for (int kk = 0; kk < 2; ++kk) {
            int r = p0 + pi * 16 + m;
            rA[pi][kk] = (r * 128 + kk * 64 + kg * 16) ^ swz(r);
        }
#pragma unroll
    for (int ni = 0; ni < 2; ++ni)
#pragma unroll
        for (int kk = 0; kk < 2; ++kk) {
            int rn = n0 + ni * 16 + m;
            rB[ni][kk] = 8192 + ((rn * 128 + kk * 64 + kg * 16) ^ swz(rn));
        }

    f32x4 acc[2][2];
#pragma unroll
    for (int i = 0; i < 2; ++i)
#pragma unroll
        for (int j = 0; j < 2; ++j) acc[i][j] = (f32x4){0.f, 0.f, 0.f, 0.f};

    f32x4 xr0, xr1, br[2][2];
    float wv0, wv1;

#define LOADR(it)                                                              \
    {                                                                          \
        size_t ax = (size_t)(it) * (TT * NH * PDIM);                           \
        size_t ab = (size_t)(it) * (TT * NH * NDIM);                           \
        xr0 = *(const f32x4*)(xsrc + ax);                                      \
        xr1 = *(const f32x4*)(xsrc + ax + NH * PDIM);                          \
        br[0][0] = *(const f32x4*)(bsrc + ab);                                 \
        br[0][1] = *(const f32x4*)(bsrc + ab + NH * NDIM);                     \
        br[1][0] = *(const f32x4*)(bsrc + ab + 32 * NH * NDIM);                \
        br[1][1] = *(const f32x4*)(bsrc + ab + 33 * NH * NDIM);                \
    }

#define LOADW(it)                                                              \
    {                                                                          \
        wv0 = wlds[(it) * TT + 2 * tpx];                                       \
        wv1 = wlds[(it) * TT + 2 * tpx + 1];                                   \
    }

#define CVTW(buf)                                                              \
    {                                                                          \
        char* dst = lds[buf];                                                  \
        _Pragma("unroll") for (int i = 0; i < 4; ++i) {                        \
            *(unsigned*)(dst + wX[i]) = pack2(xr0[i] * wv0, xr1[i] * wv1);     \
            *(unsigned*)(dst + wB0[i]) = pack2(br[0][0][i], br[0][1][i]);      \
            *(unsigned*)(dst + wB1[i]) = pack2(br[1][0][i], br[1][1][i]);      \
        }                                                                      \
    }

#define COMPUTE(buf)                                                           \
    {                                                                          \
        const char* src = lds[buf];                                            \
        short8 af[2][2], bf[2][2];                                             \
        _Pragma("unroll") for (int pi = 0; pi < 2; ++pi)                       \
            _Pragma("unroll") for (int kk = 0; kk < 2; ++kk)                   \
                af[pi][kk] = *(const short8*)(src + rA[pi][kk]);               \
        _Pragma("unroll") for (int ni = 0; ni < 2; ++ni)                       \
            _Pragma("unroll") for (int kk = 0; kk < 2; ++kk)                   \
                bf[ni][kk] = *(const short8*)(src + rB[ni][kk]);               \
        _Pragma("unroll") for (int kk = 0; kk < 2; ++kk)                       \
            _Pragma("unroll") for (int pi = 0; pi < 2; ++pi)                   \
                _Pragma("unroll") for (int ni = 0; ni < 2; ++ni)               \
                    acc[pi][ni] = __builtin_amdgcn_mfma_f32_16x16x32_bf16(     \
                        af[pi][kk], bf[ni][kk], acc[pi][ni], 0, 0, 0);         \
    }

    // issue first tile's global loads early; weight math hides under them
    LOADR(0);

    // ---- in-block suffix weights: w[i] = exp(Stail + slice_suffix(i)) ----
    // tail sum over t >= t0+KB (A is 2MB, L2/L3-resident, shared across blocks)
    {
        float s = 0.f;
        for (int t = t0 + KB + tid; t < SLEN; t += 512) s += Ab[(size_t)t * NH];
        scratch[tid] = s;
        __syncthreads();
        for (int off = 256; off > 0; off >>= 1) {
            if (tid < off) scratch[tid] += scratch[tid + off];
            __syncthreads();
        }
        float Stail = scratch[0];
        __syncthreads();

        // slice inclusive scan (Hillis-Steele over 512 thread-partials)
        constexpr int E = (KB + 511) / 512;  // consecutive elems per thread
        float loc[E > 0 ? E : 1];
        float run = 0.f;
        int base = tid * E;
#pragma unroll
        for (int e = 0; e < E; ++e) {
            int idx = base + e;
            if (idx < KB) { run += Ab[(size_t)(t0 + idx) * NH]; loc[e] = run; }
        }
        scratch[tid] = run;
        __syncthreads();
        for (int off = 1; off < 512; off <<= 1) {
            float v = (tid >= off) ? scratch[tid - off] : 0.f;
            __syncthreads();
            scratch[tid] += v;
            __syncthreads();
        }
        float incl = scratch[tid];
        float tot = scratch[511];
        float excl = incl - run;
        float basew = Stail + tot;
#pragma unroll
        for (int e = 0; e < E; ++e) {
            int idx = base + e;
            if (idx < KB) wlds[idx] = expf(basew - (excl + loc[e]));
        }
        __syncthreads();
    }

    LOADW(0);
    CVTW(0);
    __syncthreads();
    int cur = 0;
    for (int it = 0; it < NT; ++it) {
        if (it + 1 < NT) LOADR(it + 1);
        COMPUTE(cur);
        __syncthreads();
        if (it + 1 < NT) {
            LOADW(it + 1);
            CVTW(cur ^ 1);
        }
        __syncthreads();
        cur ^= 1;
    }
#undef LOADR
#undef LOADW
#undef CVTW
#undef COMPUTE

    float* outp = partial + ((size_t)ks * NBH + bh) * (PDIM * NDIM);
#pragma unroll
    for (int pi = 0; pi < 2; ++pi)
#pragma unroll
        for (int ni = 0; ni < 2; ++ni)
#pragma unroll
            for (int r = 0; r < 4; ++r) {
                int p = p0 + pi * 16 + kg * 4 + r;  // C/D: row=(lane>>4)*4+reg
                int n = n0 + ni * 16 + m;           // C/D: col=lane&15
                outp[p * NDIM + n] = acc[pi][ni][r];
            }
}

// ---------------- Kernel 2: reduce K-split partials (float4) -------------------
__global__ void reduce_kernel(const float* __restrict__ partial, float* __restrict__ out,
                              int ksplit) {
    int i = blockIdx.x * 256 + threadIdx.x;  // float4 index
    const f32x4* pp = (const f32x4*)partial;
    f32x4 s = (f32x4){0.f, 0.f, 0.f, 0.f};
    for (int ks = 0; ks < ksplit; ++ks) {
        f32x4 v = pp[(size_t)ks * (NBH * PDIM * NDIM / 4) + i];
        s.x += v.x; s.y += v.y; s.z += v.z; s.w += v.w;
    }
    ((f32x4*)out)[i] = s;
}

extern "C" void kernel_launch(void* const* d_in, const int* in_sizes, int n_in,
                              void* d_out, int out_size, void* d_ws, size_t ws_size,
                              hipStream_t stream) {
    const float* X = (const float*)d_in[0];
    const float* A = (const float*)d_in[1];
    const float* Bm = (const float*)d_in[2];
    // d_in[3] (C) is unused by the reference.
    float* out = (float*)d_out;

    float* partial = (float*)d_ws;
    size_t slice_bytes = (size_t)NBH * PDIM * NDIM * sizeof(float);

    if (ws_size < (size_t)KSPLIT * slice_bytes) {
        // degenerate fallback: single K-slice (full sequence) straight into out
        state_gemm_kernel<SLEN, SLEN / TT><<<dim3(1, NBH), 512, 0, stream>>>(X, Bm, A, out);
        return;
    }
    state_gemm_kernel<SLEN / KSPLIT, SLEN / KSPLIT / TT>
        <<<dim3(KSPLIT, NBH), 512, 0, stream>>>(X, Bm, A, partial);
    int nout4 = NBH * PDIM * NDIM / 4;
    reduce_kernel<<<nout4 / 256, 256, 0, stream>>>(partial, out, KSPLIT);
}

// Round 5
// 29.849 us; speedup vs baseline: 1.3857x; 1.0728x over previous
//
#include <hip/hip_runtime.h>
#include <hip/hip_bf16.h>

#define SLEN 4096
#define NH 16
#define PDIM 64
#define NDIM 128
#define NBH 32   // b*h
#define KSPLIT 16
#define TT 64    // t per LDS tile

typedef __attribute__((ext_vector_type(8))) short short8;
typedef __attribute__((ext_vector_type(4))) float f32x4;

// swizzle: spreads ds_read_b128 (rows consecutive) and transpose ds_write_b32
// (rows stride-4, 4 t-cols per wave) across the 8 16B slots of a 128B row
__device__ __forceinline__ int swz(int r) { return ((r & 7) ^ ((r >> 2) & 7)) << 4; }

__device__ __forceinline__ unsigned short f2bfu(float x) {
    __hip_bfloat16 h = __float2bfloat16(x);
    return *reinterpret_cast<unsigned short*>(&h);
}
__device__ __forceinline__ unsigned pack2(float lo, float hi) {
    return (unsigned)f2bfu(lo) | ((unsigned)f2bfu(hi) << 16);
}

// ---------------- Fused kernel: in-block suffix weights + LDS-staged GEMM -----
// out[p,n] += sum_t (w[t]*X[t,p]) * B[t,n] over this block's K-slice, where
// w[t] = exp(sum_{t'>t} A[t']) computed in-block (shfl scan, hidden under loads).
// Block: 512 thr = 8 waves (2p x 4n); wave = 32p x 32n (2x2 frags 16x16x32).
// LDS buffer: X=[64p][64t] bf16 (8KB) + B=[128n][64t] bf16 (16KB), double-buffered.
// Register prefetch depth 2 (both banks in flight), 1 barrier per tile.
template <int KB, int NT>
__global__ __launch_bounds__(512, 4) void state_gemm_kernel(
    const float* __restrict__ X, const float* __restrict__ Bm,
    const float* __restrict__ A, float* __restrict__ partial) {
    int ks = blockIdx.x;
    int bh = blockIdx.y;
    int b = bh >> 4, h = bh & 15;
    int tid = threadIdx.x;
    int lane = tid & 63, wv_ = tid >> 6;
    int wp = wv_ & 1, wn = wv_ >> 1;
    int p0 = wp * 32, n0 = wn * 32;
    int m = lane & 15, kg = lane >> 4;
    int c = tid & 15, tp = tid >> 4;  // staging: feature-group c, t-pair tp (0..31)

    __shared__ __align__(16) char lds[2][24576];  // X at 0, B at 8192
    __shared__ float wlds[KB];

    const float* Xb = X + (size_t)b * (SLEN * NH * PDIM) + h * PDIM;
    const float* Bb = Bm + (size_t)b * (SLEN * NH * NDIM) + h * NDIM;
    const float* Ab = A + (size_t)b * (SLEN * NH) + h;  // stride NH
    int t0 = ks * KB;

    const float* xsrc = Xb + (size_t)(t0 + 2 * tp) * (NH * PDIM) + 4 * c;
    const float* bsrc = Bb + (size_t)(t0 + 2 * tp) * (NH * NDIM) + 4 * c;

    // staging write byte offsets: row r=4c+i, t-col pair tp. B rows at +8192
    // (n=4c+i) and +16384 (n=4c+i+64); swz(r+64)==swz(r) so offsets share wX.
    int wX[4];
#pragma unroll
    for (int i = 0; i < 4; ++i) {
        int r = 4 * c + i;
        wX[i] = (r * 128 + 4 * tp) ^ swz(r);
    }
    // fragment read byte offsets
    int rA[2][2], rB[2][2];
#pragma unroll
    for (int pi = 0; pi < 2; ++pi)
#pragma unroll
        for (int kk = 0; kk < 2; ++kk) {
            int r = p0 + pi * 16 + m;
            rA[pi][kk] = (r * 128 + kk * 64 + kg * 16) ^ swz(r);
        }
#pragma unroll
    for (int ni = 0; ni < 2; ++ni)
#pragma unroll
        for (int kk = 0; kk < 2; ++kk) {
            int rn = n0 + ni * 16 + m;
            rB[ni][kk] = 8192 + ((rn * 128 + kk * 64 + kg * 16) ^ swz(rn));
        }

    f32x4 acc[2][2];
#pragma unroll
    for (int i = 0; i < 2; ++i)
#pragma unroll
        for (int j = 0; j < 2; ++j) acc[i][j] = (f32x4){0.f, 0.f, 0.f, 0.f};

    // two register banks for depth-2 prefetch
    f32x4 rx0[2], rx1[2], rb00[2], rb01[2], rb10[2], rb11[2];

#define LOADR(it, bk)                                                          \
    {                                                                          \
        const float* xp = xsrc + (size_t)(it) * (TT * NH * PDIM);              \
        const float* bp = bsrc + (size_t)(it) * (TT * NH * NDIM);              \
        rx0[bk] = *(const f32x4*)(xp);                                         \
        rx1[bk] = *(const f32x4*)(xp + NH * PDIM);                             \
        rb00[bk] = *(const f32x4*)(bp);                                        \
        rb01[bk] = *(const f32x4*)(bp + NH * NDIM);                            \
        rb10[bk] = *(const f32x4*)(bp + 64);                                   \
        rb11[bk] = *(const f32x4*)(bp + NH * NDIM + 64);                       \
    }

#define CVTW(buf, bk, it)                                                      \
    {                                                                          \
        float wv0 = wlds[(it) * TT + 2 * tp];                                  \
        float wv1 = wlds[(it) * TT + 2 * tp + 1];                              \
        char* dst = lds[buf];                                                  \
        _Pragma("unroll") for (int i = 0; i < 4; ++i) {                        \
            *(unsigned*)(dst + wX[i]) = pack2(rx0[bk][i] * wv0, rx1[bk][i] * wv1); \
            *(unsigned*)(dst + wX[i] + 8192) = pack2(rb00[bk][i], rb01[bk][i]);    \
            *(unsigned*)(dst + wX[i] + 16384) = pack2(rb10[bk][i], rb11[bk][i]);   \
        }                                                                      \
    }

#define COMPUTE(buf)                                                           \
    {                                                                          \
        const char* src = lds[buf];                                            \
        short8 af[2][2], bf[2][2];                                             \
        _Pragma("unroll") for (int pi = 0; pi < 2; ++pi)                       \
            _Pragma("unroll") for (int kk = 0; kk < 2; ++kk)                   \
                af[pi][kk] = *(const short8*)(src + rA[pi][kk]);               \
        _Pragma("unroll") for (int ni = 0; ni < 2; ++ni)                       \
            _Pragma("unroll") for (int kk = 0; kk < 2; ++kk)                   \
                bf[ni][kk] = *(const short8*)(src + rB[ni][kk]);               \
        _Pragma("unroll") for (int kk = 0; kk < 2; ++kk)                       \
            _Pragma("unroll") for (int pi = 0; pi < 2; ++pi)                   \
                _Pragma("unroll") for (int ni = 0; ni < 2; ++ni)               \
                    acc[pi][ni] = __builtin_amdgcn_mfma_f32_16x16x32_bf16(     \
                        af[pi][kk], bf[ni][kk], acc[pi][ni], 0, 0, 0);         \
    }

    // prologue: put 12 loads (2 tiles) in flight before anything else
    LOADR(0, 0);
    if (NT > 1) LOADR(1, 1);

    // ---- suffix weights via wave shfl scan (hides under the in-flight loads)
    {
        float* sc = (float*)(lds[1]);  // 16-float scratch; lds[1] unwritten yet
        float ts = 0.f;
        for (int t = t0 + KB + tid; t < SLEN; t += 512) ts += Ab[(size_t)t * NH];
        constexpr int E = (KB + 511) / 512;
        float loc[E];
        float run = 0.f;
        int base = tid * E;
#pragma unroll
        for (int e = 0; e < E; ++e) {
            int idx = base + e;
            if (idx < KB) { run += Ab[(size_t)(t0 + idx) * NH]; loc[e] = run; }
        }
        float v = run;
#pragma unroll
        for (int off = 1; off < 64; off <<= 1) {
            float u = __shfl_up(v, off, 64);
            if (lane >= off) v += u;
        }
#pragma unroll
        for (int off = 32; off > 0; off >>= 1) ts += __shfl_xor(ts, off, 64);
        if (lane == 63) sc[wv_] = v;       // per-wave slice sum
        if (lane == 0) sc[8 + wv_] = ts;   // per-wave tail sum
        __syncthreads();
        float woff = 0.f, tot = 0.f, stail = 0.f;
#pragma unroll
        for (int q = 0; q < 8; ++q) {
            float s_ = sc[q];
            tot += s_;
            if (q < wv_) woff += s_;
            stail += sc[8 + q];
        }
        float excl = woff + v - run;
        float basew = stail + tot;
#pragma unroll
        for (int e = 0; e < E; ++e) {
            int idx = base + e;
            if (idx < KB) wlds[idx] = expf(basew - (excl + loc[e]));
        }
        __syncthreads();
    }

    CVTW(0, 0, 0);
    __syncthreads();

#pragma unroll
    for (int it = 0; it < NT; ++it) {
        if (it + 2 < NT) LOADR(it + 2, it & 1);        // issue 2 tiles ahead
        COMPUTE(it & 1);                                // tile it lives in buf it&1
        if (it + 1 < NT) CVTW((it + 1) & 1, (it + 1) & 1, it + 1);
        __syncthreads();
    }
#undef LOADR
#undef CVTW
#undef COMPUTE

    float* outp = partial + ((size_t)ks * NBH + bh) * (PDIM * NDIM);
#pragma unroll
    for (int pi = 0; pi < 2; ++pi)
#pragma unroll
        for (int ni = 0; ni < 2; ++ni)
#pragma unroll
            for (int r = 0; r < 4; ++r) {
                int p = p0 + pi * 16 + kg * 4 + r;  // C/D: row=(lane>>4)*4+reg
                int n = n0 + ni * 16 + m;           // C/D: col=lane&15
                outp[p * NDIM + n] = acc[pi][ni][r];
            }
}

// ---------------- Kernel 2: reduce K-split partials (float4) -------------------
__global__ void reduce_kernel(const float* __restrict__ partial, float* __restrict__ out,
                              int ksplit) {
    int i = blockIdx.x * 256 + threadIdx.x;  // float4 index
    const f32x4* pp = (const f32x4*)partial;
    f32x4 s = (f32x4){0.f, 0.f, 0.f, 0.f};
    for (int ks = 0; ks < ksplit; ++ks) {
        f32x4 v = pp[(size_t)ks * (NBH * PDIM * NDIM / 4) + i];
        s.x += v.x; s.y += v.y; s.z += v.z; s.w += v.w;
    }
    ((f32x4*)out)[i] = s;
}

extern "C" void kernel_launch(void* const* d_in, const int* in_sizes, int n_in,
                              void* d_out, int out_size, void* d_ws, size_t ws_size,
                              hipStream_t stream) {
    const float* X = (const float*)d_in[0];
    const float* A = (const float*)d_in[1];
    const float* Bm = (const float*)d_in[2];
    // d_in[3] (C) is unused by the reference.
    float* out = (float*)d_out;

    float* partial = (float*)d_ws;
    size_t slice_bytes = (size_t)NBH * PDIM * NDIM * sizeof(float);

    if (ws_size < (size_t)KSPLIT * slice_bytes) {
        // degenerate fallback: single K-slice (full sequence) straight into out
        state_gemm_kernel<SLEN, SLEN / TT><<<dim3(1, NBH), 512, 0, stream>>>(X, Bm, A, out);
        return;
    }
    state_gemm_kernel<SLEN / KSPLIT, SLEN / KSPLIT / TT>
        <<<dim3(KSPLIT, NBH), 512, 0, stream>>>(X, Bm, A, partial);
    int nout4 = NBH * PDIM * NDIM / 4;
    reduce_kernel<<<nout4 / 256, 256, 0, stream>>>(partial, out, KSPLIT);
}

// Round 6
// 29.693 us; speedup vs baseline: 1.3930x; 1.0053x over previous
//
#include <hip/hip_runtime.h>
#include <hip/hip_bf16.h>

#define SLEN 4096
#define NH 16
#define PDIM 64
#define NDIM 128
#define NBH 32   // b*h
#define KSPLIT 16
#define TT 64    // t per LDS tile

typedef __attribute__((ext_vector_type(8))) short short8;
typedef __attribute__((ext_vector_type(4))) float f32x4;

// raw barrier: LDS ordering via lgkmcnt only — does NOT drain vmcnt, so
// register-prefetch global loads stay in flight across the barrier (T4).
#define BAR()                                                                  \
    {                                                                          \
        asm volatile("s_waitcnt lgkmcnt(0)" ::: "memory");                     \
        __builtin_amdgcn_sched_barrier(0);                                     \
        __builtin_amdgcn_s_barrier();                                          \
    }

// swizzle: spreads ds_read_b128 (rows consecutive) and transpose ds_write_b32
// (rows stride-4, 4 t-cols per wave) across the 8 16B slots of a 128B row
__device__ __forceinline__ int swz(int r) { return ((r & 7) ^ ((r >> 2) & 7)) << 4; }

__device__ __forceinline__ unsigned short f2bfu(float x) {
    __hip_bfloat16 h = __float2bfloat16(x);
    return *reinterpret_cast<unsigned short*>(&h);
}
__device__ __forceinline__ unsigned pack2(float lo, float hi) {
    return (unsigned)f2bfu(lo) | ((unsigned)f2bfu(hi) << 16);
}

// ---------------- Fused kernel: in-block suffix weights + LDS-staged GEMM -----
// out[p,n] += sum_t (w[t]*X[t,p]) * B[t,n] over this block's K-slice, where
// w[t] = exp(sum_{t'>t} A[t']) computed in-block (shfl scan, hidden under loads).
// Block: 512 thr = 8 waves (2p x 4n); wave = 32p x 32n (2x2 frags 16x16x32).
// LDS buffer: X=[64p][64t] bf16 (8KB) + B=[128n][64t] bf16 (16KB), double-buffered.
// Register prefetch depth 2; raw barriers keep prefetch loads in flight.
template <int KB, int NT>
__global__ __launch_bounds__(512, 4) void state_gemm_kernel(
    const float* __restrict__ X, const float* __restrict__ Bm,
    const float* __restrict__ A, float* __restrict__ partial) {
    int ks = blockIdx.x;
    int bh = blockIdx.y;
    int b = bh >> 4, h = bh & 15;
    int tid = threadIdx.x;
    int lane = tid & 63, wv_ = tid >> 6;
    int wp = wv_ & 1, wn = wv_ >> 1;
    int p0 = wp * 32, n0 = wn * 32;
    int m = lane & 15, kg = lane >> 4;
    int c = tid & 15, tp = tid >> 4;  // staging: feature-group c, t-pair tp (0..31)

    __shared__ __align__(16) char lds[2][24576];  // X at 0, B at 8192
    __shared__ float wlds[KB];

    const float* Xb = X + (size_t)b * (SLEN * NH * PDIM) + h * PDIM;
    const float* Bb = Bm + (size_t)b * (SLEN * NH * NDIM) + h * NDIM;
    const float* Ab = A + (size_t)b * (SLEN * NH) + h;  // stride NH
    int t0 = ks * KB;

    const float* xsrc = Xb + (size_t)(t0 + 2 * tp) * (NH * PDIM) + 4 * c;
    const float* bsrc = Bb + (size_t)(t0 + 2 * tp) * (NH * NDIM) + 4 * c;

    // staging write byte offsets: row r=4c+i, t-col pair tp. B rows at +8192
    // (n=4c+i) and +16384 (n=4c+i+64); swz(r+64)==swz(r) so offsets share wX.
    int wX[4];
#pragma unroll
    for (int i = 0; i < 4; ++i) {
        int r = 4 * c + i;
        wX[i] = (r * 128 + 4 * tp) ^ swz(r);
    }
    // fragment read byte offsets
    int rA[2][2], rB[2][2];
#pragma unroll
    for (int pi = 0; pi < 2; ++pi)
#pragma unroll
        for (int kk = 0; kk < 2; ++kk) {
            int r = p0 + pi * 16 + m;
            rA[pi][kk] = (r * 128 + kk * 64 + kg * 16) ^ swz(r);
        }
#pragma unroll
    for (int ni = 0; ni < 2; ++ni)
#pragma unroll
        for (int kk = 0; kk < 2; ++kk) {
            int rn = n0 + ni * 16 + m;
            rB[ni][kk] = 8192 + ((rn * 128 + kk * 64 + kg * 16) ^ swz(rn));
        }

    f32x4 acc[2][2];
#pragma unroll
    for (int i = 0; i < 2; ++i)
#pragma unroll
        for (int j = 0; j < 2; ++j) acc[i][j] = (f32x4){0.f, 0.f, 0.f, 0.f};

    // two register banks for depth-2 prefetch
    f32x4 rx0[2], rx1[2], rb00[2], rb01[2], rb10[2], rb11[2];

#define LOADR(it, bk)                                                          \
    {                                                                          \
        const float* xp = xsrc + (size_t)(it) * (TT * NH * PDIM);              \
        const float* bp = bsrc + (size_t)(it) * (TT * NH * NDIM);              \
        rx0[bk] = *(const f32x4*)(xp);                                         \
        rx1[bk] = *(const f32x4*)(xp + NH * PDIM);                             \
        rb00[bk] = *(const f32x4*)(bp);                                        \
        rb01[bk] = *(const f32x4*)(bp + NH * NDIM);                            \
        rb10[bk] = *(const f32x4*)(bp + 64);                                   \
        rb11[bk] = *(const f32x4*)(bp + NH * NDIM + 64);                       \
    }

#define CVTW(buf, bk, it)                                                      \
    {                                                                          \
        float wv0 = wlds[(it) * TT + 2 * tp];                                  \
        float wv1 = wlds[(it) * TT + 2 * tp + 1];                              \
        char* dst = lds[buf];                                                  \
        _Pragma("unroll") for (int i = 0; i < 4; ++i) {                        \
            *(unsigned*)(dst + wX[i]) = pack2(rx0[bk][i] * wv0, rx1[bk][i] * wv1); \
            *(unsigned*)(dst + wX[i] + 8192) = pack2(rb00[bk][i], rb01[bk][i]);    \
            *(unsigned*)(dst + wX[i] + 16384) = pack2(rb10[bk][i], rb11[bk][i]);   \
        }                                                                      \
    }

#define COMPUTE(buf)                                                           \
    {                                                                          \
        const char* src = lds[buf];                                            \
        short8 af[2][2], bf[2][2];                                             \
        _Pragma("unroll") for (int pi = 0; pi < 2; ++pi)                       \
            _Pragma("unroll") for (int kk = 0; kk < 2; ++kk)                   \
                af[pi][kk] = *(const short8*)(src + rA[pi][kk]);               \
        _Pragma("unroll") for (int ni = 0; ni < 2; ++ni)                       \
            _Pragma("unroll") for (int kk = 0; kk < 2; ++kk)                   \
                bf[ni][kk] = *(const short8*)(src + rB[ni][kk]);               \
        _Pragma("unroll") for (int kk = 0; kk < 2; ++kk)                       \
            _Pragma("unroll") for (int pi = 0; pi < 2; ++pi)                   \
                _Pragma("unroll") for (int ni = 0; ni < 2; ++ni)               \
                    acc[pi][ni] = __builtin_amdgcn_mfma_f32_16x16x32_bf16(     \
                        af[pi][kk], bf[ni][kk], acc[pi][ni], 0, 0, 0);         \
    }

    // prologue: put 12 loads (2 tiles) in flight before anything else
    LOADR(0, 0);
    if (NT > 1) LOADR(1, 1);

    // ---- suffix weights via wave shfl scan (hides under the in-flight loads)
    {
        float* sc = (float*)(lds[1]);  // 16-float scratch; lds[1] unwritten yet
        float ts = 0.f;
        for (int t = t0 + KB + tid; t < SLEN; t += 512) ts += Ab[(size_t)t * NH];
        constexpr int E = (KB + 511) / 512;
        float loc[E];
        float run = 0.f;
        int base = tid * E;
#pragma unroll
        for (int e = 0; e < E; ++e) {
            int idx = base + e;
            if (idx < KB) { run += Ab[(size_t)(t0 + idx) * NH]; loc[e] = run; }
        }
        float v = run;
#pragma unroll
        for (int off = 1; off < 64; off <<= 1) {
            float u = __shfl_up(v, off, 64);
            if (lane >= off) v += u;
        }
#pragma unroll
        for (int off = 32; off > 0; off >>= 1) ts += __shfl_xor(ts, off, 64);
        if (lane == 63) sc[wv_] = v;       // per-wave slice sum
        if (lane == 0) sc[8 + wv_] = ts;   // per-wave tail sum
        BAR();
        float woff = 0.f, tot = 0.f, stail = 0.f;
#pragma unroll
        for (int q = 0; q < 8; ++q) {
            float s_ = sc[q];
            tot += s_;
            if (q < wv_) woff += s_;
            stail += sc[8 + q];
        }
        float excl = woff + v - run;
        float basew = stail + tot;
#pragma unroll
        for (int e = 0; e < E; ++e) {
            int idx = base + e;
            if (idx < KB) wlds[idx] = expf(basew - (excl + loc[e]));
        }
        BAR();
    }

    CVTW(0, 0, 0);
    BAR();

#pragma unroll
    for (int it = 0; it < NT; ++it) {
        if (it + 2 < NT) LOADR(it + 2, it & 1);        // issue 2 tiles ahead
        COMPUTE(it & 1);                                // tile it lives in buf it&1
        if (it + 1 < NT) CVTW((it + 1) & 1, (it + 1) & 1, it + 1);
        BAR();  // lgkm-only: prefetch vmcnt stays in flight across the barrier
    }
#undef LOADR
#undef CVTW
#undef COMPUTE

    float* outp = partial + ((size_t)ks * NBH + bh) * (PDIM * NDIM);
#pragma unroll
    for (int pi = 0; pi < 2; ++pi)
#pragma unroll
        for (int ni = 0; ni < 2; ++ni)
#pragma unroll
            for (int r = 0; r < 4; ++r) {
                int p = p0 + pi * 16 + kg * 4 + r;  // C/D: row=(lane>>4)*4+reg
                int n = n0 + ni * 16 + m;           // C/D: col=lane&15
                outp[p * NDIM + n] = acc[pi][ni][r];
            }
}

// ---------------- Kernel 2: reduce K-split partials (float4) -------------------
__global__ void reduce_kernel(const float* __restrict__ partial, float* __restrict__ out,
                              int ksplit) {
    int i = blockIdx.x * 256 + threadIdx.x;  // float4 index
    const f32x4* pp = (const f32x4*)partial;
    f32x4 s = (f32x4){0.f, 0.f, 0.f, 0.f};
    for (int ks = 0; ks < ksplit; ++ks) {
        f32x4 v = pp[(size_t)ks * (NBH * PDIM * NDIM / 4) + i];
        s.x += v.x; s.y += v.y; s.z += v.z; s.w += v.w;
    }
    ((f32x4*)out)[i] = s;
}

extern "C" void kernel_launch(void* const* d_in, const int* in_sizes, int n_in,
                              void* d_out, int out_size, void* d_ws, size_t ws_size,
                              hipStream_t stream) {
    const float* X = (const float*)d_in[0];
    const float* A = (const float*)d_in[1];
    const float* Bm = (const float*)d_in[2];
    // d_in[3] (C) is unused by the reference.
    float* out = (float*)d_out;

    float* partial = (float*)d_ws;
    size_t slice_bytes = (size_t)NBH * PDIM * NDIM * sizeof(float);

    if (ws_size < (size_t)KSPLIT * slice_bytes) {
        // degenerate fallback: single K-slice (full sequence) straight into out
        state_gemm_kernel<SLEN, SLEN / TT><<<dim3(1, NBH), 512, 0, stream>>>(X, Bm, A, out);
        return;
    }
    state_gemm_kernel<SLEN / KSPLIT, SLEN / KSPLIT / TT>
        <<<dim3(KSPLIT, NBH), 512, 0, stream>>>(X, Bm, A, partial);
    int nout4 = NBH * PDIM * NDIM / 4;
    reduce_kernel<<<nout4 / 256, 256, 0, stream>>>(partial, out, KSPLIT);
}